// Round 11
// baseline (125.147 us; speedup 1.0000x reference)
//
#include <hip/hip_runtime.h>

// FlashAttention fwd, causal. B=2, S=2048, H=16, D=64, fp32 in/out.
// Layout [B,S,H,D]: row (b,s,h) is 64 contiguous floats; s-stride = 1024 floats.
//
// R19: LDS-staged K/V chunks + (mt,kvh) wave split -> 5 waves/SIMD.
// R18 post-mortem: prepack hypothesis REFUTED (coalesced rewrite = +1.4us
// noise); (total - fa_fwd) ~ 80us is harness-fixed; fa_fwd (42us, ~39%
// issue-packed, 40% latency bubbles at 4 waves) is the only lever.
// Occupancy ledger: R9/R11/R14/R17 all spilled adding waves REGISTER-side.
// R19 adds the 5th wave STRUCTURALLY: block = 32-row tile, chunk = 64kv;
// waves = (mt = 16-q-rows) x (kvh = 32-kv slice). Chunk K+V (16KB) staged
// ONCE per block into double-buffered LDS via global_load_lds (zero-VGPR,
// dest = uniform base + lane*16 -- the m104-legal pattern, proven by R17's
// V path); waves ds_read_b128 fragments as SHORT-LIVED transients.
// Per-wave state: qf 8 + acc 16A + accL 4A + ones 4 + transients (kc16/vc16
// overlapping, s8, up4) + addr ~6 -> peak ~82 unified vs cap 102 (first
// attempt with real margin; R17 was ~100 vs 96). L2 traffic stays at the
// compulsory 0.58GB (each K/V byte read once per block) -- the register-only
// 16m variant would double it to 1.1GB ~= the L2 ceiling; rejected.
// LDS: 2 x 16KB chunk bufs = 32KB (20KB Red aliased after) -> exactly
// 5 blocks/CU = 5 waves/SIMD (+25% latency hiding). One barrier per
// chunk-iter; 5 resident blocks cover each other's barrier bubbles.
// Per-wave causal bound myEnd skips fully-masked chunk COMPUTE (staging +
// barrier stay block-uniform). Spill tripwire: WRITE_SIZE ~16.4MB.
//
// K32-PV trick (verified R14-R18): concat of the two P^T C-frags has slot
// order kv(lhi,j) = (j<4) ? 4*lhi+j : 16+4*lhi+(j-4), a bijection on 0..31;
// prepack stores V rows pre-permuted into that slot order -> exact dot.
// Envelope: 2048 longest-first single-tile blocks; bh = id&31 same-head ->
// same-XCD; staging overruns land inside the 256MB workspace, never consumed.
//
// prepack (R18 verbatim, verified): coalesced float4 -> LDS[64][68] ->
// coalesced 16B fragment-linear stores. Output layouts:
//   Kp: quarter q (16 kv rows): 2KB at (bh*128+q)*2048B; lane 16B at
//     ks*1024 + lane*16 = K[s=16q+llo][d=ks*32+lhi*8 ..+8] (K32 A-frag).
//   Vp (permuted K32 B-frag): group g (32 kv rows): 4KB at (bh*64+g)*4096B;
//     16B unit at dt*1024 + lane*16, slot j = V[kv=32g+perm(lhi,j)][d=dt*16+llo].

typedef __bf16  bf16x8_t  __attribute__((ext_vector_type(8)));
typedef short   short8_t  __attribute__((ext_vector_type(8)));
typedef float   f32x4     __attribute__((ext_vector_type(4)));

#define MFMA_K32(a, b, c) __builtin_amdgcn_mfma_f32_16x16x32_bf16((a), (b), (c), 0, 0, 0)
#define BC8(x) __builtin_bit_cast(bf16x8_t, (x))

constexpr int   SEQ = 2048, NH = 16;
constexpr int   SROW = NH * 64;                       // 1024 floats between s
constexpr float QS   = 0.125f * 1.44269504088896f;    // 1/sqrt(64) * log2(e)

__device__ __forceinline__ unsigned f2bfu(float f) {
    unsigned u = __builtin_bit_cast(unsigned, f);
    return (u + 0x7fffu + ((u >> 16) & 1u)) >> 16;
}
__device__ __forceinline__ unsigned pk2(float x, float y) {
#if defined(__HIP_DEVICE_COMPILE__) && __has_builtin(__builtin_amdgcn_cvt_pk_bf16_f32)
    typedef __bf16 bfv2 __attribute__((ext_vector_type(2)));
    bfv2 v = __builtin_amdgcn_cvt_pk_bf16_f32(x, y);
    return __builtin_bit_cast(unsigned, v);
#else
    return (f2bfu(x) & 0xffffu) | (f2bfu(y) << 16);
#endif
}

// async global(16B/lane) -> LDS (wave-uniform base + lane*16), zero VGPR dest
__device__ __forceinline__ void gload_lds16(const void* g, void* l) {
#if defined(__HIP_DEVICE_COMPILE__)
    __builtin_amdgcn_global_load_lds(
        (const __attribute__((address_space(1))) unsigned*)g,
        (__attribute__((address_space(3))) unsigned*)l, 16, 0, 0);
#endif
}

// ---------------- pre-pass: coalesced load -> LDS transpose -> coalesced store ----------------
__global__ __launch_bounds__(256) void prepack(const float* __restrict__ K,
                                               const float* __restrict__ V,
                                               unsigned short* __restrict__ Kp,
                                               unsigned short* __restrict__ Vp) {
    const int blk = blockIdx.x;          // 1024 = bh*32 + chunk(64 rows)
    const int tid = threadIdx.x;
    const int bh = blk >> 5, c = blk & 31;
    const int b  = bh >> 4,  h = bh & 15;

    __shared__ float LK[64][68];
    __shared__ float LV[64][68];

    const float* Ksrc = K + (size_t)(b * SEQ + c * 64) * SROW + h * 64;
    const float* Vsrc = V + (size_t)(b * SEQ + c * 64) * SROW + h * 64;

#pragma unroll
    for (int p = 0; p < 4; ++p) {
        const int f   = p * 256 + tid;
        const int row = f >> 4;
        const int c4  = (f & 15) * 4;
        float4 kk = *(const float4*)(Ksrc + (size_t)row * SROW + c4);
        float4 vv = *(const float4*)(Vsrc + (size_t)row * SROW + c4);
        *(float4*)&LK[row][c4] = kk;
        *(float4*)&LV[row][c4] = vv;
    }
    __syncthreads();

#pragma unroll
    for (int u = tid; u < 512; u += 256) {
        const int q_l = u >> 7, ks = (u >> 6) & 1, lane = u & 63;
        const int lhi = lane >> 4, llo = lane & 15;
        const float* r = &LK[q_l * 16 + llo][ks * 32 + lhi * 8];
        uint4 o;
        o.x = pk2(r[0], r[1]); o.y = pk2(r[2], r[3]);
        o.z = pk2(r[4], r[5]); o.w = pk2(r[6], r[7]);
        *(uint4*)(Kp + (size_t)(bh * 128 + c * 4) * 1024 + u * 8) = o;
    }

#pragma unroll
    for (int u = tid; u < 512; u += 256) {
        const int g_l = u >> 8, dt = (u >> 6) & 3, lane = u & 63;
        const int lhi = lane >> 4, llo = lane & 15;
        const int d   = dt * 16 + llo;
        const int kvb = g_l * 32 + lhi * 4;
        uint4 o;
        o.x = pk2(LV[kvb + 0][d],  LV[kvb + 1][d]);
        o.y = pk2(LV[kvb + 2][d],  LV[kvb + 3][d]);
        o.z = pk2(LV[kvb + 16][d], LV[kvb + 17][d]);
        o.w = pk2(LV[kvb + 18][d], LV[kvb + 19][d]);
        *(uint4*)(Vp + (size_t)(bh * 64 + c * 2) * 2048 + u * 8) = o;
    }
}

// ---------------- main kernel ----------------
__global__ __launch_bounds__(256, 5) void fa_fwd(const float* __restrict__ Q,
                                                 const unsigned short* __restrict__ Kp,
                                                 const unsigned short* __restrict__ Vp,
                                                 float* __restrict__ O) {
    const int id = blockIdx.x;
    const int bh = id & 31;            // id%8 fixed per head -> XCD locality
    const int T  = 63 - (id >> 5);     // 32-row tile index, longest first
    const int b  = bh >> 4, h = bh & 15;
    const int NSC = (T >> 1) + 1;      // 64-kv chunks (block-uniform)
    const int q0  = T * 32;

    const int tid  = threadIdx.x;
    const int w    = tid >> 6;
    const int mt   = w >> 1;           // wave's 16-row half of the tile
    const int kvh  = w & 1;            // wave's 32-kv slice of each chunk
    const int lane = tid & 63;
    const int lhi  = lane >> 4;
    const int llo  = lane & 15;

    // 32KB: 2 staging bufs x 1024 uint4 (K = elems [0,512), V = [512,1024));
    // Red[4][5][64][4] (20KB) aliased after the loop's final barrier.
    __shared__ __align__(16) uint4 KV[2][1024];

    const char* Ku = (const char*)Kp + ((size_t)bh << 18);
    const char* Vu = (const char*)Vp + ((size_t)bh << 18);

    // Q fragments for this wave's mt (log2e * scale folded in)
    bf16x8_t qf[2];
#pragma unroll
    for (int ks = 0; ks < 2; ++ks) {
        const float* qp = Q + (size_t)(b * SEQ + q0 + mt * 16 + llo) * SROW + h * 64 + ks * 32 + lhi * 8;
        float4 a = ((const float4*)qp)[0], c4 = ((const float4*)qp)[1];
        uint4 u;
        u.x = pk2(a.x * QS, a.y * QS); u.y = pk2(a.z * QS, a.w * QS);
        u.z = pk2(c4.x * QS, c4.y * QS); u.w = pk2(c4.z * QS, c4.w * QS);
        qf[ks] = __builtin_bit_cast(bf16x8_t, u);
    }

    f32x4 acc[4], accL;
    accL = (f32x4){0.f, 0.f, 0.f, 0.f};
#pragma unroll
    for (int dt = 0; dt < 4; ++dt) acc[dt] = (f32x4){0.f, 0.f, 0.f, 0.f};

    short8_t o8;
#pragma unroll
    for (int j = 0; j < 8; ++j) o8[j] = (short)0x3F80;   // bf16 1.0
    const bf16x8_t ones8 = __builtin_bit_cast(bf16x8_t, o8);

    const int m0  = q0 + mt * 16;
    const int m_g = m0 + llo;
    // wave's needed chunks (<= NSC); beyond: fully masked, compute skipped
    const int myEnd = ((m0 + 15 - (kvh << 5)) >> 6) + 1;
    const int kb0   = kvh << 5;

    // ---- prologue: stage chunk 0 into buf0 (K 8KB + V 8KB, 4 x 16B/thread) ----
    {
        const char* ks0 = Ku + tid * 16;
        const char* vs0 = Vu + tid * 16;
        gload_lds16(ks0,        &KV[0][tid]);
        gload_lds16(ks0 + 4096, &KV[0][tid + 256]);
        gload_lds16(vs0,        &KV[0][tid + 512]);
        gload_lds16(vs0 + 4096, &KV[0][tid + 768]);
    }
    __syncthreads();                     // implies vmcnt(0): staging landed

    for (int sc = 0; sc < NSC; ++sc) {
        const int cb = sc & 1, nb = cb ^ 1;

        // ---- stage chunk sc+1 into the other buffer (drained by the bottom
        //      barrier after ~570cy of compute; overrun stays in workspace) ----
        {
            const char* ksrc = Ku + (size_t)(sc + 1) * 8192 + tid * 16;
            const char* vsrc = Vu + (size_t)(sc + 1) * 8192 + tid * 16;
            gload_lds16(ksrc,        &KV[nb][tid]);
            gload_lds16(ksrc + 4096, &KV[nb][tid + 256]);
            gload_lds16(vsrc,        &KV[nb][tid + 512]);
            gload_lds16(vsrc + 4096, &KV[nb][tid + 768]);
        }

        if (sc < myEnd) {                // wave-uniform; skips fully-masked chunks
            const int kbase = (kvh << 8) + lane;          // kvh*256 + lane
            uint4 kc0 = KV[cb][kbase];
            uint4 kc1 = KV[cb][kbase + 64];
            uint4 kc2 = KV[cb][kbase + 128];
            uint4 kc3 = KV[cb][kbase + 192];
            uint4 vc0 = KV[cb][kbase + 512];
            uint4 vc1 = KV[cb][kbase + 576];
            uint4 vc2 = KV[cb][kbase + 640];
            uint4 vc3 = KV[cb][kbase + 704];

            // ---- S^T: 32kv x 16m, 4 K32 (2 independent 2-chains) ----
            __builtin_amdgcn_s_setprio(1);
            f32x4 s0 = (f32x4){0.f, 0.f, 0.f, 0.f};
            f32x4 s1 = (f32x4){0.f, 0.f, 0.f, 0.f};
            s0 = MFMA_K32(BC8(kc0), qf[0], s0);
            s1 = MFMA_K32(BC8(kc2), qf[0], s1);
            s0 = MFMA_K32(BC8(kc1), qf[1], s0);
            s1 = MFMA_K32(BC8(kc3), qf[1], s1);
            __builtin_amdgcn_s_setprio(0);

            // ---- causal mask (diagonal chunks only; wave-uniform predicates) ----
            const int kb = (sc << 6) + kb0;
            if (kb + 15 > m0) {
#pragma unroll
                for (int r = 0; r < 4; ++r)
                    if (kb + lhi * 4 + r > m_g) s0[r] = -INFINITY;
            }
            if (kb + 31 > m0) {
#pragma unroll
                for (int r = 0; r < 4; ++r)
                    if (kb + 16 + lhi * 4 + r > m_g) s1[r] = -INFINITY;
            }

            // ---- P = exp2(s); concat C-frags = permuted K32 A-frag ----
            uint4 up;
            up.x = pk2(__builtin_amdgcn_exp2f(s0[0]), __builtin_amdgcn_exp2f(s0[1]));
            up.y = pk2(__builtin_amdgcn_exp2f(s0[2]), __builtin_amdgcn_exp2f(s0[3]));
            up.z = pk2(__builtin_amdgcn_exp2f(s1[0]), __builtin_amdgcn_exp2f(s1[1]));
            up.w = pk2(__builtin_amdgcn_exp2f(s1[2]), __builtin_amdgcn_exp2f(s1[3]));
            const bf16x8_t pf = BC8(up);

            // ---- O += P.V ; rowsum via ones ----
            __builtin_amdgcn_s_setprio(1);
            acc[0] = MFMA_K32(pf, BC8(vc0), acc[0]);
            acc[1] = MFMA_K32(pf, BC8(vc1), acc[1]);
            acc[2] = MFMA_K32(pf, BC8(vc2), acc[2]);
            acc[3] = MFMA_K32(pf, BC8(vc3), acc[3]);
            accL   = MFMA_K32(pf, ones8, accL);
            __builtin_amdgcn_s_setprio(0);
        }

        __syncthreads();   // staging of nxt landed; all waves done reading cur
    }

    // ---- tile end: sum the two kvh partials per mt; single barrier ----
    typedef float RedT[5][64][4];
    RedT* Red = (RedT*)(void*)KV;          // 20KB alias, safe after final barrier
#pragma unroll
    for (int dt = 0; dt < 4; ++dt) *(f32x4*)&Red[w][dt][lane][0] = acc[dt];
    *(f32x4*)&Red[w][4][lane][0] = accL;
    __syncthreads();

    const int wa = mt << 1, wb = wa + 1;   // the two kvh waves of this mt
    f32x4 ls = *(const f32x4*)&Red[wa][4][lane][0] + *(const f32x4*)&Red[wb][4][lane][0];
    f32x4 inv;
#pragma unroll
    for (int r = 0; r < 4; ++r) inv[r] = 1.0f / ls[r];

#pragma unroll
    for (int i = 0; i < 2; ++i) {
        const int dt = (kvh << 1) + i;     // wave writes d-cols [kvh*32, +32)
        f32x4 oc = *(const f32x4*)&Red[wa][dt][lane][0] + *(const f32x4*)&Red[wb][dt][lane][0];
#pragma unroll
        for (int r = 0; r < 4; ++r)
            O[(size_t)(b * SEQ + q0 + mt * 16 + lhi * 4 + r) * SROW + h * 64 + dt * 16 + llo] = oc[r] * inv[r];
    }
}

extern "C" void kernel_launch(void* const* d_in, const int* in_sizes, int n_in,
                              void* d_out, int out_size, void* d_ws, size_t ws_size,
                              hipStream_t stream) {
    const float* q = (const float*)d_in[0];
    const float* k = (const float*)d_in[1];
    const float* v = (const float*)d_in[2];
    float* o = (float*)d_out;
    unsigned short* Kp = (unsigned short*)d_ws;
    unsigned short* Vp = Kp + (size_t)32 * 32 * 4096;   // 8MB each, 16MB total
    prepack<<<dim3(1024), dim3(256), 0, stream>>>(k, v, Kp, Vp);
    fa_fwd<<<dim3(2048), dim3(256), 0, stream>>>(q, Kp, Vp, o);
}